// Round 3
// baseline (1020.896 us; speedup 1.0000x reference)
//
#include <hip/hip_runtime.h>

#define IN_C 64
#define OUT_C 128
#define HID 32
#define KNB 16
#define NEG 0.1f

__device__ __forceinline__ float leaky(float v, float s) { return fmaxf(v, s * v); }

// ---------------- K1: h = leaky(x @ W_in + b_in, 0.1) ----------------
// SPLIT threads per point: each computes CH=16 hidden channels.
__global__ __launch_bounds__(256) void hid_kernel2(
    const float* __restrict__ x, const float* __restrict__ Win,
    const float* __restrict__ bin, float* __restrict__ h, int P)
{
    int t = blockIdx.x * blockDim.x + threadIdx.x;
    if (t >= 2 * P) return;
    int p = t >> 1;
    int c0 = (t & 1) * 16;

    float xr[IN_C];
    const float4* x4 = (const float4*)(x + (long)p * IN_C);
    #pragma unroll
    for (int i = 0; i < IN_C / 4; ++i) {
        float4 v = x4[i];
        xr[4 * i + 0] = v.x; xr[4 * i + 1] = v.y;
        xr[4 * i + 2] = v.z; xr[4 * i + 3] = v.w;
    }

    float acc[16];
    #pragma unroll
    for (int c = 0; c < 16; ++c) acc[c] = bin[c0 + c];

    #pragma unroll 8
    for (int k = 0; k < IN_C; ++k) {
        float xv = xr[k];
        #pragma unroll
        for (int c = 0; c < 16; ++c) acc[c] = fmaf(xv, Win[k * HID + c0 + c], acc[c]);
    }

    float4* h4 = (float4*)(h + (long)p * HID + c0);
    #pragma unroll
    for (int c2 = 0; c2 < 4; ++c2) {
        float4 v;
        v.x = leaky(acc[4 * c2 + 0], NEG);
        v.y = leaky(acc[4 * c2 + 1], NEG);
        v.z = leaky(acc[4 * c2 + 2], NEG);
        v.w = leaky(acc[4 * c2 + 3], NEG);
        h4[c2] = v;
    }
}

// ---------------- K2: conv partials over edges ----------------
// EH threads per point; thread handles KNB/EH edges, writes [P][EH][32].
template<int EH>
__global__ __launch_bounds__(256) void edge_kernel(
    const float* __restrict__ pos, const int* __restrict__ nbr,
    const float* __restrict__ h,
    const float* __restrict__ Wa, const float* __restrict__ ba,
    const float* __restrict__ Wb, const float* __restrict__ bb,
    float* __restrict__ convp, int N, int P)
{
    int t = blockIdx.x * blockDim.x + threadIdx.x;
    if (t >= EH * P) return;
    int p    = t / EH;
    int half = t % EH;
    const int EDG = KNB / EH;

    long pbase = (p >= N) ? (long)N : 0;

    float px = pos[3L * p + 0];
    float py = pos[3L * p + 1];
    float pz = pos[3L * p + 2];

    float conv[HID];
    #pragma unroll
    for (int c = 0; c < HID; ++c) conv[c] = 0.f;

    const int* nrow = nbr + (long)p * KNB + half * EDG;
    int  j = nrow[0];
    long q = pbase + j;
    float qx = pos[3 * q + 0], qy = pos[3 * q + 1], qz = pos[3 * q + 2];

    #pragma unroll 1
    for (int e = 0; e < EDG; ++e) {
        const float4* h4 = (const float4*)(h + q * HID);
        float4 hg0 = h4[0], hg1 = h4[1], hg2 = h4[2], hg3 = h4[3];
        float4 hg4 = h4[4], hg5 = h4[5], hg6 = h4[6], hg7 = h4[7];

        float rx = px - qx, ry = py - qy, rz = pz - qz;

        if (e < EDG - 1) {
            j = nrow[e + 1];
            q = pbase + j;
            qx = pos[3 * q + 0]; qy = pos[3 * q + 1]; qz = pos[3 * q + 2];
        }

        float tt[HID];
        #pragma unroll
        for (int c = 0; c < HID; ++c) {
            float v = fmaf(rx, Wa[c], fmaf(ry, Wa[HID + c], fmaf(rz, Wa[2 * HID + c], ba[c])));
            tt[c] = leaky(v, NEG);
        }

        float hgv[HID] = {
            hg0.x, hg0.y, hg0.z, hg0.w,  hg1.x, hg1.y, hg1.z, hg1.w,
            hg2.x, hg2.y, hg2.z, hg2.w,  hg3.x, hg3.y, hg3.z, hg3.w,
            hg4.x, hg4.y, hg4.z, hg4.w,  hg5.x, hg5.y, hg5.z, hg5.w,
            hg6.x, hg6.y, hg6.z, hg6.w,  hg7.x, hg7.y, hg7.z, hg7.w };

        #pragma unroll
        for (int c = 0; c < HID; ++c) {
            float wv = bb[c];
            #pragma unroll
            for (int jj = 0; jj < HID; ++jj) wv = fmaf(tt[jj], Wb[jj * HID + c], wv);
            conv[c] = fmaf(wv, hgv[c], conv[c]);
        }
    }

    float4* cp4 = (float4*)(convp + ((long)p * EH + half) * HID);
    #pragma unroll
    for (int i = 0; i < HID / 4; ++i) {
        float4 v;
        v.x = conv[4 * i + 0]; v.y = conv[4 * i + 1];
        v.z = conv[4 * i + 2]; v.w = conv[4 * i + 3];
        cp4[i] = v;
    }
}

// ---------------- K3: out = leaky(conv@Wout + x@Wsc + bout + bsc, 0.01) ----
// 2 threads per point, 64 outputs each; sums NPART conv partials.
template<int NPART>
__global__ __launch_bounds__(256) void gemv_kernel(
    const float* __restrict__ x, const float* __restrict__ convp,
    const float* __restrict__ Wout, const float* __restrict__ bout,
    const float* __restrict__ Wsc, const float* __restrict__ bsc,
    float* __restrict__ out, int P)
{
    int t = blockIdx.x * blockDim.x + threadIdx.x;
    if (t >= 2 * P) return;
    int p     = t >> 1;
    int obase = (t & 1) * 64;

    float cv[HID];
    {
        const float4* cp4 = (const float4*)(convp + (long)p * NPART * HID);
        #pragma unroll
        for (int i = 0; i < HID / 4; ++i) {
            float4 v = cp4[i];
            if (NPART == 2) {
                float4 v2 = cp4[HID / 4 + i];
                v.x += v2.x; v.y += v2.y; v.z += v2.z; v.w += v2.w;
            }
            cv[4 * i + 0] = v.x; cv[4 * i + 1] = v.y;
            cv[4 * i + 2] = v.z; cv[4 * i + 3] = v.w;
        }
    }

    float xr[IN_C];
    const float4* x4 = (const float4*)(x + (long)p * IN_C);
    #pragma unroll
    for (int i = 0; i < IN_C / 4; ++i) {
        float4 v = x4[i];
        xr[4 * i + 0] = v.x; xr[4 * i + 1] = v.y;
        xr[4 * i + 2] = v.z; xr[4 * i + 3] = v.w;
    }

    float* op = out + (long)p * OUT_C;
    #pragma unroll 1
    for (int chunk = 0; chunk < 8; ++chunk) {
        int o0 = obase + chunk * 8;
        float a[8];
        #pragma unroll
        for (int l = 0; l < 8; ++l) a[l] = bout[o0 + l] + bsc[o0 + l];
        #pragma unroll
        for (int c = 0; c < HID; ++c) {
            float v = cv[c];
            const float* wr = Wout + c * OUT_C + o0;
            #pragma unroll
            for (int l = 0; l < 8; ++l) a[l] = fmaf(v, wr[l], a[l]);
        }
        #pragma unroll
        for (int k = 0; k < IN_C; ++k) {
            float v = xr[k];
            const float* wr = Wsc + k * OUT_C + o0;
            #pragma unroll
            for (int l = 0; l < 8; ++l) a[l] = fmaf(v, wr[l], a[l]);
        }
        float4 v0, v1;
        v0.x = leaky(a[0], 0.01f); v0.y = leaky(a[1], 0.01f);
        v0.z = leaky(a[2], 0.01f); v0.w = leaky(a[3], 0.01f);
        v1.x = leaky(a[4], 0.01f); v1.y = leaky(a[5], 0.01f);
        v1.z = leaky(a[6], 0.01f); v1.w = leaky(a[7], 0.01f);
        *(float4*)(op + o0 + 0) = v0;
        *(float4*)(op + o0 + 4) = v1;
    }
}

// ---------------- fallback: round-1 monolithic point kernel ----------------
__global__ __launch_bounds__(256) void point_mono(
    const float* __restrict__ x, const float* __restrict__ pos,
    const int* __restrict__ nbr, const float* __restrict__ h,
    const float* __restrict__ Wa, const float* __restrict__ ba,
    const float* __restrict__ Wb, const float* __restrict__ bb,
    const float* __restrict__ Wout, const float* __restrict__ bout,
    const float* __restrict__ Wsc, const float* __restrict__ bsc,
    float* __restrict__ out, int N, int P)
{
    int p = blockIdx.x * blockDim.x + threadIdx.x;
    if (p >= P) return;
    long pbase = (p >= N) ? (long)N : 0;

    float px = pos[3L * p], py = pos[3L * p + 1], pz = pos[3L * p + 2];

    float xr[IN_C];
    const float4* x4 = (const float4*)(x + (long)p * IN_C);
    #pragma unroll
    for (int i = 0; i < IN_C / 4; ++i) {
        float4 v = x4[i];
        xr[4 * i] = v.x; xr[4 * i + 1] = v.y; xr[4 * i + 2] = v.z; xr[4 * i + 3] = v.w;
    }

    float conv[HID];
    #pragma unroll
    for (int c = 0; c < HID; ++c) conv[c] = 0.f;

    #pragma unroll 1
    for (int e = 0; e < KNB; ++e) {
        long q = pbase + nbr[(long)p * KNB + e];
        float rx = px - pos[3 * q], ry = py - pos[3 * q + 1], rz = pz - pos[3 * q + 2];
        float hgv[HID];
        const float4* h4 = (const float4*)(h + q * HID);
        #pragma unroll
        for (int i = 0; i < HID / 4; ++i) {
            float4 v = h4[i];
            hgv[4 * i] = v.x; hgv[4 * i + 1] = v.y; hgv[4 * i + 2] = v.z; hgv[4 * i + 3] = v.w;
        }
        float tt[HID];
        #pragma unroll
        for (int c = 0; c < HID; ++c) {
            float v = fmaf(rx, Wa[c], fmaf(ry, Wa[HID + c], fmaf(rz, Wa[2 * HID + c], ba[c])));
            tt[c] = leaky(v, NEG);
        }
        #pragma unroll
        for (int c = 0; c < HID; ++c) {
            float wv = bb[c];
            #pragma unroll
            for (int jj = 0; jj < HID; ++jj) wv = fmaf(tt[jj], Wb[jj * HID + c], wv);
            conv[c] = fmaf(wv, hgv[c], conv[c]);
        }
    }

    float* op = out + (long)p * OUT_C;
    #pragma unroll 1
    for (int o = 0; o < OUT_C; o += 8) {
        float a[8];
        #pragma unroll
        for (int l = 0; l < 8; ++l) a[l] = bout[o + l] + bsc[o + l];
        #pragma unroll
        for (int c = 0; c < HID; ++c) {
            float v = conv[c];
            const float* wr = Wout + c * OUT_C + o;
            #pragma unroll
            for (int l = 0; l < 8; ++l) a[l] = fmaf(v, wr[l], a[l]);
        }
        #pragma unroll
        for (int k = 0; k < IN_C; ++k) {
            float v = xr[k];
            const float* wr = Wsc + k * OUT_C + o;
            #pragma unroll
            for (int l = 0; l < 8; ++l) a[l] = fmaf(v, wr[l], a[l]);
        }
        float4 v0, v1;
        v0.x = leaky(a[0], 0.01f); v0.y = leaky(a[1], 0.01f);
        v0.z = leaky(a[2], 0.01f); v0.w = leaky(a[3], 0.01f);
        v1.x = leaky(a[4], 0.01f); v1.y = leaky(a[5], 0.01f);
        v1.z = leaky(a[6], 0.01f); v1.w = leaky(a[7], 0.01f);
        *(float4*)(op + o) = v0;
        *(float4*)(op + o + 4) = v1;
    }
}

extern "C" void kernel_launch(void* const* d_in, const int* in_sizes, int n_in,
                              void* d_out, int out_size, void* d_ws, size_t ws_size,
                              hipStream_t stream) {
    const float* x    = (const float*)d_in[0];
    const float* pos  = (const float*)d_in[1];
    const int*   nbr  = (const int*)d_in[2];
    const float* Win  = (const float*)d_in[3];
    const float* bin  = (const float*)d_in[4];
    const float* Wa   = (const float*)d_in[5];
    const float* ba   = (const float*)d_in[6];
    const float* Wb   = (const float*)d_in[7];
    const float* bb   = (const float*)d_in[8];
    const float* Wout = (const float*)d_in[9];
    const float* bout = (const float*)d_in[10];
    const float* Wsc  = (const float*)d_in[11];
    const float* bsc  = (const float*)d_in[12];
    float* out = (float*)d_out;

    int P = in_sizes[0] / IN_C;   // B*N
    int N = P / 2;                // B = 2 per reference

    float* h = (float*)d_ws;                       // P*HID floats
    size_t need2 = (size_t)P * (HID + 2 * HID) * 4;  // h + 2 partials
    size_t need1 = (size_t)P * (HID + HID) * 4;      // h + 1 partial

    hid_kernel2<<<(2 * P + 255) / 256, 256, 0, stream>>>(x, Win, bin, h, P);

    if (ws_size >= need2) {
        float* convp = h + (size_t)P * HID;
        edge_kernel<2><<<(2 * P + 255) / 256, 256, 0, stream>>>(
            pos, nbr, h, Wa, ba, Wb, bb, convp, N, P);
        gemv_kernel<2><<<(2 * P + 255) / 256, 256, 0, stream>>>(
            x, convp, Wout, bout, Wsc, bsc, out, P);
    } else if (ws_size >= need1) {
        float* convp = h + (size_t)P * HID;
        edge_kernel<1><<<(P + 255) / 256, 256, 0, stream>>>(
            pos, nbr, h, Wa, ba, Wb, bb, convp, N, P);
        gemv_kernel<1><<<(2 * P + 255) / 256, 256, 0, stream>>>(
            x, convp, Wout, bout, Wsc, bsc, out, P);
    } else {
        point_mono<<<(P + 255) / 256, 256, 0, stream>>>(
            x, pos, nbr, h, Wa, ba, Wb, bb, Wout, bout, Wsc, bsc, out, N, P);
    }
}

// Round 4
// 637.281 us; speedup vs baseline: 1.6020x; 1.6020x over previous
//
#include <hip/hip_runtime.h>

#define IN_C 64
#define OUT_C 128
#define HID 32
#define KNB 16
#define NEG 0.1f

__device__ __forceinline__ float leaky(float v, float s) { return fmaxf(v, s * v); }

// ---------------- K1: h = leaky(x @ W_in + b_in, 0.1)  [P,64]->[P,32] -------
// One lane per point; all weight addresses wave-uniform -> s_load broadcasts.
__global__ __launch_bounds__(256) void hid_kernel(
    const float* __restrict__ x, const float* __restrict__ Win,
    const float* __restrict__ bin, float* __restrict__ h, int P)
{
    int p = blockIdx.x * blockDim.x + threadIdx.x;
    if (p >= P) return;

    float xr[IN_C];
    const float4* x4 = (const float4*)(x + (long)p * IN_C);
    #pragma unroll
    for (int i = 0; i < IN_C / 4; ++i) {
        float4 v = x4[i];
        xr[4 * i + 0] = v.x; xr[4 * i + 1] = v.y;
        xr[4 * i + 2] = v.z; xr[4 * i + 3] = v.w;
    }

    float acc[HID];
    #pragma unroll
    for (int c = 0; c < HID; ++c) acc[c] = bin[c];

    #pragma unroll 8
    for (int k = 0; k < IN_C; ++k) {
        float xv = xr[k];
        #pragma unroll
        for (int c = 0; c < HID; ++c) acc[c] = fmaf(xv, Win[k * HID + c], acc[c]);
    }

    float4* h4 = (float4*)(h + (long)p * HID);
    #pragma unroll
    for (int c2 = 0; c2 < HID / 4; ++c2) {
        float4 v;
        v.x = leaky(acc[4 * c2 + 0], NEG);
        v.y = leaky(acc[4 * c2 + 1], NEG);
        v.z = leaky(acc[4 * c2 + 2], NEG);
        v.w = leaky(acc[4 * c2 + 3], NEG);
        h4[c2] = v;
    }
}

// ---------------- K2: monolithic per-point kernel (R1 structure + ILP) ------
// One thread per point. Edge loop double-buffers the gathered h row and the
// neighbor position so the gather latency hides under the 32x32 GEMM.
// All weight reads are wave-uniform -> scalar cache. (256,1): full VGPR
// budget; grid is 2 waves/SIMD regardless, so occupancy is unaffected.
__global__ __launch_bounds__(256, 1) void point_kernel(
    const float* __restrict__ x, const float* __restrict__ pos,
    const int* __restrict__ nbr, const float* __restrict__ h,
    const float* __restrict__ Wa, const float* __restrict__ ba,
    const float* __restrict__ Wb, const float* __restrict__ bb,
    const float* __restrict__ Wout, const float* __restrict__ bout,
    const float* __restrict__ Wsc, const float* __restrict__ bsc,
    float* __restrict__ out, int N, int P)
{
    int p = blockIdx.x * blockDim.x + threadIdx.x;
    if (p >= P) return;
    long pbase = (p >= N) ? (long)N : 0;   // per-batch index base (B=2)

    float px = pos[3L * p + 0];
    float py = pos[3L * p + 1];
    float pz = pos[3L * p + 2];

    float conv[HID];
    #pragma unroll
    for (int c = 0; c < HID; ++c) conv[c] = 0.f;

    const int* nrow = nbr + (long)p * KNB;

    // ---- peel: load edge 0 (idx, neighbor pos, gathered h row) ----
    long q0 = pbase + nrow[0];
    float qx = pos[3 * q0 + 0], qy = pos[3 * q0 + 1], qz = pos[3 * q0 + 2];
    const float4* h4 = (const float4*)(h + q0 * HID);
    float4 c0 = h4[0], c1 = h4[1], c2 = h4[2], c3 = h4[3];
    float4 c4 = h4[4], c5 = h4[5], c6 = h4[6], c7 = h4[7];

    #pragma unroll 1
    for (int e = 0; e < KNB; ++e) {
        float rx = px - qx, ry = py - qy, rz = pz - qz;

        // ---- prefetch edge e+1 (hides under the GEMM below) ----
        float4 n0, n1, n2, n3, n4, n5, n6, n7;
        float nqx, nqy, nqz;
        bool more = (e < KNB - 1);
        if (more) {
            long qn = pbase + nrow[e + 1];
            nqx = pos[3 * qn + 0]; nqy = pos[3 * qn + 1]; nqz = pos[3 * qn + 2];
            const float4* nh4 = (const float4*)(h + qn * HID);
            n0 = nh4[0]; n1 = nh4[1]; n2 = nh4[2]; n3 = nh4[3];
            n4 = nh4[4]; n5 = nh4[5]; n6 = nh4[6]; n7 = nh4[7];
        }

        // ---- t = leaky(rel @ Wa + ba, 0.1) ----
        float t[HID];
        #pragma unroll
        for (int c = 0; c < HID; ++c) {
            float v = fmaf(rx, Wa[c], fmaf(ry, Wa[HID + c], fmaf(rz, Wa[2 * HID + c], ba[c])));
            t[c] = leaky(v, NEG);
        }

        // ---- w = t @ Wb + bb ; conv += w * hg ----
        float hgv[HID] = {
            c0.x, c0.y, c0.z, c0.w,  c1.x, c1.y, c1.z, c1.w,
            c2.x, c2.y, c2.z, c2.w,  c3.x, c3.y, c3.z, c3.w,
            c4.x, c4.y, c4.z, c4.w,  c5.x, c5.y, c5.z, c5.w,
            c6.x, c6.y, c6.z, c6.w,  c7.x, c7.y, c7.z, c7.w };

        #pragma unroll
        for (int c = 0; c < HID; ++c) {
            float wv = bb[c];
            #pragma unroll
            for (int jj = 0; jj < HID; ++jj) wv = fmaf(t[jj], Wb[jj * HID + c], wv);
            conv[c] = fmaf(wv, hgv[c], conv[c]);
        }

        // ---- rotate double buffer ----
        if (more) {
            c0 = n0; c1 = n1; c2 = n2; c3 = n3;
            c4 = n4; c5 = n5; c6 = n6; c7 = n7;
            qx = nqx; qy = nqy; qz = nqz;
        }
    }

    // ---- GEMV: out = leaky(conv@Wout + x@Wsc + bout + bsc, 0.01) ----
    // x row loaded here (not held across the edge loop) to cap register peak.
    float xr[IN_C];
    const float4* x4 = (const float4*)(x + (long)p * IN_C);
    #pragma unroll
    for (int i = 0; i < IN_C / 4; ++i) {
        float4 v = x4[i];
        xr[4 * i + 0] = v.x; xr[4 * i + 1] = v.y;
        xr[4 * i + 2] = v.z; xr[4 * i + 3] = v.w;
    }

    float* op = out + (long)p * OUT_C;
    #pragma unroll 1
    for (int chunk = 0; chunk < OUT_C / 8; ++chunk) {
        int o0 = chunk * 8;
        float a[8];
        #pragma unroll
        for (int l = 0; l < 8; ++l) a[l] = bout[o0 + l] + bsc[o0 + l];
        #pragma unroll
        for (int c = 0; c < HID; ++c) {
            float v = conv[c];
            const float* wr = Wout + c * OUT_C + o0;
            #pragma unroll
            for (int l = 0; l < 8; ++l) a[l] = fmaf(v, wr[l], a[l]);
        }
        #pragma unroll
        for (int k = 0; k < IN_C; ++k) {
            float v = xr[k];
            const float* wr = Wsc + k * OUT_C + o0;
            #pragma unroll
            for (int l = 0; l < 8; ++l) a[l] = fmaf(v, wr[l], a[l]);
        }
        float4 v0, v1;
        v0.x = leaky(a[0], 0.01f); v0.y = leaky(a[1], 0.01f);
        v0.z = leaky(a[2], 0.01f); v0.w = leaky(a[3], 0.01f);
        v1.x = leaky(a[4], 0.01f); v1.y = leaky(a[5], 0.01f);
        v1.z = leaky(a[6], 0.01f); v1.w = leaky(a[7], 0.01f);
        *(float4*)(op + o0 + 0) = v0;
        *(float4*)(op + o0 + 4) = v1;
    }
}

extern "C" void kernel_launch(void* const* d_in, const int* in_sizes, int n_in,
                              void* d_out, int out_size, void* d_ws, size_t ws_size,
                              hipStream_t stream) {
    const float* x    = (const float*)d_in[0];
    const float* pos  = (const float*)d_in[1];
    const int*   nbr  = (const int*)d_in[2];
    const float* Win  = (const float*)d_in[3];
    const float* bin  = (const float*)d_in[4];
    const float* Wa   = (const float*)d_in[5];
    const float* ba   = (const float*)d_in[6];
    const float* Wb   = (const float*)d_in[7];
    const float* bb   = (const float*)d_in[8];
    const float* Wout = (const float*)d_in[9];
    const float* bout = (const float*)d_in[10];
    const float* Wsc  = (const float*)d_in[11];
    const float* bsc  = (const float*)d_in[12];
    float* out = (float*)d_out;

    int P = in_sizes[0] / IN_C;   // B*N
    int N = P / 2;                // B = 2 per reference
    float* h = (float*)d_ws;      // P*HID floats

    hid_kernel<<<(P + 255) / 256, 256, 0, stream>>>(x, Win, bin, h, P);
    point_kernel<<<(P + 255) / 256, 256, 0, stream>>>(
        x, pos, nbr, h, Wa, ba, Wb, bb, Wout, bout, Wsc, bsc, out, N, P);
}